// Round 7
// baseline (199.197 us; speedup 1.0000x reference)
//
#include <hip/hip_runtime.h>
#include <math.h>

#define HALO 10
#define TS 32
#define IN 42      // TS + HALO rows staged
#define NP 21      // float2 pairs staged per row (42 cols; window needs <=41)
#define ISTR 86    // interleaved row stride (words): 2*42=84 +2 pad; 86 mod 32=22, gcd 2 -> 2-way b64
#define NBIN 256   // atomic spreading: one 64B line (16 floats) per bin per level

typedef float f2 __attribute__((ext_vector_type(2)));

struct GaussW { float g[11]; };

// Series-pair interleaved layout: every LDS f2 slot holds (series_a, series_b)
// at ONE column, so ALL packed v_pk_fma_f32 operands are even-aligned VGPR
// pairs (lane pairing across series, not across columns -> no straddles).
//   staging  XY [42 rows][ISTR]  : [r][2c..2c+1] = (x, y) at (r, c)      14.4 KB
//   h-blur   HXY[32 cols][ISTR]  : [c][2r..2r+1] = (hx, hy)              |
//            HSD[32 cols][ISTR]  : [c][2r..2r+1] = (hs, hd)              | 22.0 KB
// One union region U (5504 words = 22016 B); HXY/HSD alias the staging tile
// (all XY reads complete before the barrier preceding the first H write).
// 22.0 KB LDS -> 7 blocks/CU (VGPR cap 73 at 7 waves/SIMD; expect ~45 -> no spill).

__global__ __launch_bounds__(256, 7) void ssim_level_kernel(
    const float* __restrict__ X, const float* __restrict__ Y,
    int H, GaussW gw, float* __restrict__ Plevel, int last_level,
    float* __restrict__ Xpool, float* __restrict__ Ypool)
{
    const int W = H;
    const int Hout = H - HALO;   // == Wout (square)

    __shared__ float U[2 * TS * ISTR];   // 5504 words
    __shared__ float red[4];
    float* XYs = U;                      // [IN][ISTR] staging (3612 words)
    float* HXY = U;                      // [TS][ISTR] h-blur (x,y)
    float* HSD = U + TS * ISTR;          // [TS][ISTR] h-blur (s,d)

    const int tid = threadIdx.x;
    const int bc  = blockIdx.z;          // b*3 + c
    const int b   = bc / 3;
    const int r0  = blockIdx.y * TS;
    const int c0  = blockIdx.x * TS;
    const size_t base = (size_t)bc * H * W;

    // ---- Phase 1: coalesced staging, interleaved (x,y) per column ----
    for (int idx = tid; idx < IN * NP; idx += 256) {
        int rr = idx / NP, pp = idx - rr * NP;
        int gr = r0 + rr, gc = c0 + 2 * pp;
        float2 xv = make_float2(0.f, 0.f), yv = make_float2(0.f, 0.f);
        if (gr < H && gc < W) {          // gc even, W even => gc+1 < W too
            xv = *(const float2*)(X + base + (size_t)gr * W + gc);
            yv = *(const float2*)(Y + base + (size_t)gr * W + gc);
        }
        *(f2*)&XYs[rr * ISTR + 4 * pp    ] = f2{ xv.x, yv.x };
        *(f2*)&XYs[rr * ISTR + 4 * pp + 2] = f2{ xv.y, yv.y };
    }
    __syncthreads();

    // ---- Phase 2a: window -> registers (waves 0-2); 2x2 avg-pool (wave 3) ----
    f2 w[18];
    int rr = 0, ccb = 0;
    if (tid < 168) {
        rr  = tid >> 2;
        ccb = (tid & 3) * 8;
        #pragma unroll
        for (int u = 0; u < 18; ++u)
            w[u] = *(const f2*)&XYs[rr * ISTR + 2 * (ccb + u)];
    } else if (tid >= 192 && !last_level) {
        const int t = tid - 192;
        const int Wp = W >> 1;
        #pragma unroll
        for (int q = 0; q < 4; ++q) {
            int cell = q * 64 + t;           // 0..255 -> 16x16 pool cells
            int pr = cell >> 4, pc = cell & 15;
            f2 s0 = *(const f2*)&XYs[(2 * pr)     * ISTR + 4 * pc];
            f2 s1 = *(const f2*)&XYs[(2 * pr)     * ISTR + 4 * pc + 2];
            f2 s2 = *(const f2*)&XYs[(2 * pr + 1) * ISTR + 4 * pc];
            f2 s3 = *(const f2*)&XYs[(2 * pr + 1) * ISTR + 4 * pc + 2];
            f2 sum = (s0 + s1) + (s2 + s3);  // (x-sum, y-sum) packed
            size_t o = (size_t)bc * (H >> 1) * Wp + (size_t)(r0 / 2 + pr) * Wp + (c0 / 2 + pc);
            Xpool[o] = 0.25f * sum.x;
            Ypool[o] = 0.25f * sum.y;
        }
    }
    __syncthreads();   // all XYs reads done -> HXY/HSD may overwrite the region

    // ---- Phase 2b: horizontal 11-tap blur, all-aligned packed FMA ----
    if (tid < 168) {
        // pass 1: (x, y) series-pair
        #pragma unroll
        for (int c = 0; c < 8; ++c) {
            f2 a = {0.f, 0.f};
            #pragma unroll
            for (int k = 0; k < 11; ++k) a += w[c + k] * gw.g[k];
            *(f2*)&HXY[(ccb + c) * ISTR + 2 * rr] = a;
        }
        // in-place: w[u] := ((x+y)^2, (x-y)^2)
        #pragma unroll
        for (int u = 0; u < 18; ++u) {
            float s = w[u].x + w[u].y;
            float d = w[u].x - w[u].y;
            w[u] = f2{ s, d } * f2{ s, d };
        }
        // pass 2: (s, d) series-pair
        #pragma unroll
        for (int c = 0; c < 8; ++c) {
            f2 a = {0.f, 0.f};
            #pragma unroll
            for (int k = 0; k < 11; ++k) a += w[c + k] * gw.g[k];
            *(f2*)&HSD[(ccb + c) * ISTR + 2 * rr] = a;
        }
    }
    __syncthreads();

    // ---- Phase 3: vertical 11-tap blur (aligned b64 reads, packed FMA) + SSIM ----
    const int tx = tid & 31;     // output col
    const int ty = tid >> 5;     // 0..7, owns 4 consecutive output rows
    const int rb = ty * 4;

    f2 mu[4], sd[4];             // mu[h]=(m1,m2), sd[h]=(S,D) at row rb+h
    #define VPASS(BASE, OUT)                                                     \
    {                                                                            \
        f2 v[14];                                                                \
        _Pragma("unroll")                                                        \
        for (int i = 0; i < 14; ++i)                                             \
            v[i] = *(const f2*)&BASE[tx * ISTR + 2 * (rb + i)];                  \
        _Pragma("unroll")                                                        \
        for (int h = 0; h < 4; ++h) {                                            \
            f2 acc = {0.f, 0.f};                                                 \
            _Pragma("unroll")                                                    \
            for (int k = 0; k < 11; ++k) acc += v[h + k] * gw.g[k];              \
            OUT[h] = acc;                                                        \
        }                                                                        \
    }
    VPASS(HXY, mu) VPASS(HSD, sd)
    #undef VPASS

    const float C1 = 1e-4f, C2 = 9e-4f;
    float acc_s = 0.f;
    #pragma unroll
    for (int o = 0; o < 4; ++o) {
        float u1 = mu[o].x, u2 = mu[o].y;
        float Sv = sd[o].x, Dv = sd[o].y;
        float u1s = u1 * u1, u2s = u2 * u2, u12 = u1 * u2;
        float ssum = 0.5f  * (Sv + Dv);         // blur(xx)+blur(yy)
        float sxy  = 0.25f * (Sv - Dv);         // blur(xy)
        float vsum = ssum - u1s - u2s;          // v1+v2
        float v12  = sxy - u12;
        float A2   = fmaxf(2.f * v12 + C2, 0.f);
        float B1   = u1s + u2s + C1;
        float B2   = vsum + C2;
        float inv  = __builtin_amdgcn_rcpf(B1 * B2);
        float val;
        if (!last_level) {             // levels 0-2: cs = A2/B2
            val = A2 * B1 * inv;
        } else {                       // level 3: ss = A1*A2/(B1*B2)
            float A1 = 2.f * u12 + C1;
            val = A1 * A2 * inv;
        }
        bool valid = (r0 + rb + o < Hout) && (c0 + tx < Hout);
        acc_s += valid ? val : 0.f;
    }

    // ---- Phase 4: block reduction + one atomic into a bin-spread line ----
    #pragma unroll
    for (int off = 32; off; off >>= 1) acc_s += __shfl_down(acc_s, off);
    if ((tid & 63) == 0) red[tid >> 6] = acc_s;
    __syncthreads();
    if (tid == 0) {
        int lin = blockIdx.x + gridDim.x * (blockIdx.y + gridDim.y * blockIdx.z);
        int bin = lin & (NBIN - 1);
        atomicAdd(&Plevel[bin * 16 + b], red[0] + red[1] + red[2] + red[3]);
    }
}

__global__ void finalize_kernel(const float* __restrict__ P, float* __restrict__ out) {
    __shared__ float red[64][4];
    const int tid  = threadIdx.x;      // 256
    const int pair = tid >> 2;         // 0..63 = l*16 + b
    const int chnk = tid & 3;
    const int l = pair >> 4, b = pair & 15;
    float s = 0.f;
    #pragma unroll 4
    for (int j = 0; j < 64; ++j)
        s += P[((l * NBIN) + (chnk * 64) + j) * 16 + b];
    red[pair][chnk] = s;
    __syncthreads();
    if (tid < 16) {
        const int bb = tid;
        const float wraw[4] = {0.0448f, 0.2856f, 0.3001f, 0.2363f};
        float wsum = wraw[0] + wraw[1] + wraw[2] + wraw[3];
        float ms = 1.f;
        for (int ll = 0; ll < 4; ++ll) {
            int Hh = 512 >> ll;
            int Ho = Hh - HALO;
            float cnt = 3.f * (float)Ho * (float)Ho;
            float val = (red[ll * 16 + bb][0] + red[ll * 16 + bb][1] +
                         red[ll * 16 + bb][2] + red[ll * 16 + bb][3]) / cnt;
            val = fmaxf(val, 1e-8f);
            ms *= powf(val, wraw[ll] / wsum);
        }
        out[bb] = 1.f - ms;
    }
}

extern "C" void kernel_launch(void* const* d_in, const int* in_sizes, int n_in,
                              void* d_out, int out_size, void* d_ws, size_t ws_size,
                              hipStream_t stream)
{
    const float* X0 = (const float*)d_in[0];
    const float* Y0 = (const float*)d_in[1];
    float* out = (float*)d_out;
    float* ws  = (float*)d_ws;

    // ws layout (floats): P[4][NBIN][16] | X1 | Y1 | X2 | Y2 | X3 | Y3
    const size_t PSZ = (size_t)4 * NBIN * 16;
    float* P  = ws;
    float* X1 = ws + PSZ;
    float* Y1 = X1 + (size_t)16 * 3 * 256 * 256;
    float* X2 = Y1 + (size_t)16 * 3 * 256 * 256;
    float* Y2 = X2 + (size_t)16 * 3 * 128 * 128;
    float* X3 = Y2 + (size_t)16 * 3 * 128 * 128;
    float* Y3 = X3 + (size_t)16 * 3 * 64 * 64;

    GaussW gw;
    {
        float s = 0.f;
        for (int i = 0; i < 11; ++i) {
            float d = (float)(i - 5);
            gw.g[i] = expf(-d * d / (2.f * 1.5f * 1.5f));
            s += gw.g[i];
        }
        for (int i = 0; i < 11; ++i) gw.g[i] /= s;
    }

    hipMemsetAsync(P, 0, PSZ * sizeof(float), stream);

    hipLaunchKernelGGL(ssim_level_kernel, dim3(16, 16, 48), dim3(256), 0, stream,
                       X0, Y0, 512, gw, P + 0 * NBIN * 16, 0, X1, Y1);
    hipLaunchKernelGGL(ssim_level_kernel, dim3(8, 8, 48),   dim3(256), 0, stream,
                       X1, Y1, 256, gw, P + 1 * NBIN * 16, 0, X2, Y2);
    hipLaunchKernelGGL(ssim_level_kernel, dim3(4, 4, 48),   dim3(256), 0, stream,
                       X2, Y2, 128, gw, P + 2 * NBIN * 16, 0, X3, Y3);
    hipLaunchKernelGGL(ssim_level_kernel, dim3(2, 2, 48),   dim3(256), 0, stream,
                       X3, Y3, 64,  gw, P + 3 * NBIN * 16, 1, (float*)nullptr, (float*)nullptr);

    hipLaunchKernelGGL(finalize_kernel, dim3(1), dim3(256), 0, stream, P, out);
}

// Round 9
// 189.554 us; speedup vs baseline: 1.0509x; 1.0509x over previous
//
#include <hip/hip_runtime.h>
#include <math.h>

#define HALO 10
#define TS 32
#define IN 42      // TS + HALO rows staged
#define NPV 11     // float4 units staged per row (44-col capacity, 42 used, 2 zero cols)
#define XSTR 46    // LDS row stride (words) for Xs/Ys (R6-verified bank pattern)
#define HSTR 42    // LDS row stride (words) for Hs (transposed; tx*10 mod 32 uniform)
#define NBIN 256   // atomic spreading: one 64B line (16 floats) per bin per level

typedef float f2 __attribute__((ext_vector_type(2)));

struct GaussW { float g[11]; };

// LDS plan (R6-proven): one union region U of 4*TS*HSTR words (21504 B).
//   Phase 1-2a: Xs[IN][XSTR] at U+0, Ys[IN][XSTR] at U+IN*XSTR (15456 B).
//   Phase 2b-3: Hs[4][TS][HSTR] occupies the whole region (aliases Xs/Ys).
// The alias is safe because ALL reads of Xs/Ys (register window loads + pool)
// complete before the barrier preceding the first Hs write.
// 21.5 KB LDS -> 7 blocks/CU; VGPR cap 73 at 7 waves/SIMD, kernel uses ~36-40.

__global__ __launch_bounds__(256, 7) void ssim_level_kernel(
    const float* __restrict__ X, const float* __restrict__ Y,
    int H, GaussW gw, float* __restrict__ Plevel, int last_level,
    float* __restrict__ Xpool, float* __restrict__ Ypool)
{
    const int W = H;
    const int Hout = H - HALO;   // == Wout (square)

    __shared__ float U[4 * TS * HSTR];
    __shared__ float red[4];
    float* Xs = U;                    // [IN][XSTR]
    float* Ys = U + IN * XSTR;        // [IN][XSTR]

    const int tid = threadIdx.x;
    const int bc  = blockIdx.z;          // b*3 + c
    const int b   = bc / 3;
    const int r0  = blockIdx.y * TS;
    const int c0  = blockIdx.x * TS;
    const size_t base = (size_t)bc * H * W;

    // ---- Phase 1: float4 staging (16B/lane coalescing; 1.8 iters/thread) ----
    // W % 4 == 0, gc % 4 == 0, and all buffer base offsets are 16B-aligned,
    // so gc < W implies the whole float4 is in-bounds and aligned.
    // Right-edge tiles zero-fill pp>=8; cols 42-43 are zeros, never read (<=41).
    for (int idx = tid; idx < IN * NPV; idx += 256) {
        int rr = idx / NPV, pp = idx - rr * NPV;
        int gr = r0 + rr, gc = c0 + 4 * pp;
        float4 xv = make_float4(0.f, 0.f, 0.f, 0.f);
        float4 yv = make_float4(0.f, 0.f, 0.f, 0.f);
        if (gr < H && gc < W) {
            xv = *(const float4*)(X + base + (size_t)gr * W + gc);
            yv = *(const float4*)(Y + base + (size_t)gr * W + gc);
        }
        *(f2*)&Xs[rr * XSTR + 4 * pp    ] = f2{ xv.x, xv.y };
        *(f2*)&Xs[rr * XSTR + 4 * pp + 2] = f2{ xv.z, xv.w };
        *(f2*)&Ys[rr * XSTR + 4 * pp    ] = f2{ yv.x, yv.y };
        *(f2*)&Ys[rr * XSTR + 4 * pp + 2] = f2{ yv.z, yv.w };
    }
    __syncthreads();

    // ---- Phase 2a: windows -> registers (waves 0-2); 2x2 avg-pool (wave 3) ----
    float x[18], y[18];
    int rr = 0, ccb = 0;
    if (tid < 168) {
        rr  = tid >> 2;
        ccb = (tid & 3) * 8;
        #pragma unroll
        for (int u = 0; u < 9; ++u) {
            *(f2*)&x[2 * u] = *(const f2*)&Xs[rr * XSTR + ccb + 2 * u];
            *(f2*)&y[2 * u] = *(const f2*)&Ys[rr * XSTR + ccb + 2 * u];
        }
    } else if (tid >= 192 && !last_level) {
        const int t = tid - 192;
        const int Wp = W >> 1;
        #pragma unroll
        for (int q = 0; q < 4; ++q) {
            int cell = q * 64 + t;           // 0..255 -> 16x16 pool cells
            int pr = cell >> 4, pc = cell & 15;
            float2 xa = *(const float2*)&Xs[(2 * pr)     * XSTR + 2 * pc];
            float2 xb = *(const float2*)&Xs[(2 * pr + 1) * XSTR + 2 * pc];
            float2 ya = *(const float2*)&Ys[(2 * pr)     * XSTR + 2 * pc];
            float2 yb = *(const float2*)&Ys[(2 * pr + 1) * XSTR + 2 * pc];
            size_t o = (size_t)bc * (H >> 1) * Wp + (size_t)(r0 / 2 + pr) * Wp + (c0 / 2 + pc);
            Xpool[o] = 0.25f * (xa.x + xa.y + xb.x + xb.y);
            Ypool[o] = 0.25f * (ya.x + ya.y + yb.x + yb.y);
        }
    }
    __syncthreads();   // all Xs/Ys reads done -> Hs may overwrite the region

    // ---- Phase 2b: horizontal 11-tap blur of {x, y, (x+y)^2, (x-y)^2} ----
    if (tid < 168) {
        #pragma unroll
        for (int p = 0; p < 4; ++p) {
            f2 ax = {0.f, 0.f}, ay = {0.f, 0.f};
            #pragma unroll
            for (int k = 0; k < 11; ++k) {
                f2 vx = { x[2 * p + k], x[2 * p + k + 1] };
                f2 vy = { y[2 * p + k], y[2 * p + k + 1] };
                ax += vx * gw.g[k];
                ay += vy * gw.g[k];
            }
            U[(0 * TS + ccb + 2 * p    ) * HSTR + rr] = ax.x;
            U[(0 * TS + ccb + 2 * p + 1) * HSTR + rr] = ax.y;
            U[(1 * TS + ccb + 2 * p    ) * HSTR + rr] = ay.x;
            U[(1 * TS + ccb + 2 * p + 1) * HSTR + rr] = ay.y;
        }
        // in-place: x := (x+y)^2, y := (x-y)^2 (packed; only [0..17] feed the blurs)
        #pragma unroll
        for (int i = 0; i < 9; ++i) {
            f2 xv = *(f2*)&x[2 * i];
            f2 yv = *(f2*)&y[2 * i];
            f2 a = xv + yv;
            f2 d = xv - yv;
            *(f2*)&x[2 * i] = a * a;
            *(f2*)&y[2 * i] = d * d;
        }
        #pragma unroll
        for (int p = 0; p < 4; ++p) {
            f2 as = {0.f, 0.f}, ad = {0.f, 0.f};
            #pragma unroll
            for (int k = 0; k < 11; ++k) {
                f2 vs = { x[2 * p + k], x[2 * p + k + 1] };
                f2 vd = { y[2 * p + k], y[2 * p + k + 1] };
                as += vs * gw.g[k];
                ad += vd * gw.g[k];
            }
            U[(2 * TS + ccb + 2 * p    ) * HSTR + rr] = as.x;
            U[(2 * TS + ccb + 2 * p + 1) * HSTR + rr] = as.y;
            U[(3 * TS + ccb + 2 * p    ) * HSTR + rr] = ad.x;
            U[(3 * TS + ccb + 2 * p + 1) * HSTR + rr] = ad.y;
        }
    }
    __syncthreads();

    // ---- Phase 3: vertical 11-tap blur (contiguous b64 reads, packed FMA) + SSIM ----
    const int tx = tid & 31;     // output col
    const int ty = tid >> 5;     // 0..7, owns 4 consecutive output rows
    const int rb = ty * 4;

    f2 m1[2], m2[2], S[2], D[2];
    #define VPASS(Q, OUT)                                                          \
    {                                                                              \
        float win[14];                                                             \
        _Pragma("unroll")                                                          \
        for (int i = 0; i < 7; ++i)                                                \
            *(f2*)&win[2 * i] = *(const f2*)&U[(Q * TS + tx) * HSTR + rb + 2 * i]; \
        _Pragma("unroll")                                                          \
        for (int h = 0; h < 2; ++h) {                                              \
            f2 acc = {0.f, 0.f};                                                   \
            _Pragma("unroll")                                                      \
            for (int k = 0; k < 11; ++k) {                                         \
                f2 v = { win[2 * h + k], win[2 * h + k + 1] };                     \
                acc += v * gw.g[k];                                                \
            }                                                                      \
            OUT[h] = acc;                                                          \
        }                                                                          \
    }
    VPASS(0, m1) VPASS(1, m2) VPASS(2, S) VPASS(3, D)
    #undef VPASS

    const float C1 = 1e-4f, C2 = 9e-4f;
    float acc_s = 0.f;
    #pragma unroll
    for (int o = 0; o < 4; ++o) {
        float u1 = m1[o >> 1][o & 1], u2 = m2[o >> 1][o & 1];
        float Sv = S[o >> 1][o & 1],  Dv = D[o >> 1][o & 1];
        float u1s = u1 * u1, u2s = u2 * u2, u12 = u1 * u2;
        float ssum = 0.5f  * (Sv + Dv);         // blur(xx)+blur(yy)
        float sxy  = 0.25f * (Sv - Dv);         // blur(xy)
        float vsum = ssum - u1s - u2s;          // v1+v2
        float v12  = sxy - u12;
        float A2   = fmaxf(2.f * v12 + C2, 0.f);
        float B1   = u1s + u2s + C1;
        float B2   = vsum + C2;
        float inv  = __builtin_amdgcn_rcpf(B1 * B2);
        float val;
        if (!last_level) {             // levels 0-2: cs = A2/B2
            val = A2 * B1 * inv;
        } else {                       // level 3: ss = A1*A2/(B1*B2)
            float A1 = 2.f * u12 + C1;
            val = A1 * A2 * inv;
        }
        bool valid = (r0 + rb + o < Hout) && (c0 + tx < Hout);
        acc_s += valid ? val : 0.f;
    }

    // ---- Phase 4: block reduction + one atomic into a bin-spread line ----
    #pragma unroll
    for (int off = 32; off; off >>= 1) acc_s += __shfl_down(acc_s, off);
    if ((tid & 63) == 0) red[tid >> 6] = acc_s;
    __syncthreads();
    if (tid == 0) {
        int lin = blockIdx.x + gridDim.x * (blockIdx.y + gridDim.y * blockIdx.z);
        int bin = lin & (NBIN - 1);
        atomicAdd(&Plevel[bin * 16 + b], red[0] + red[1] + red[2] + red[3]);
    }
}

__global__ void finalize_kernel(const float* __restrict__ P, float* __restrict__ out) {
    __shared__ float red[64][4];
    const int tid  = threadIdx.x;      // 256
    const int pair = tid >> 2;         // 0..63 = l*16 + b
    const int chnk = tid & 3;
    const int l = pair >> 4, b = pair & 15;
    float s = 0.f;
    #pragma unroll 4
    for (int j = 0; j < 64; ++j)
        s += P[((l * NBIN) + (chnk * 64) + j) * 16 + b];
    red[pair][chnk] = s;
    __syncthreads();
    if (tid < 16) {
        const int bb = tid;
        const float wraw[4] = {0.0448f, 0.2856f, 0.3001f, 0.2363f};
        float wsum = wraw[0] + wraw[1] + wraw[2] + wraw[3];
        float ms = 1.f;
        for (int ll = 0; ll < 4; ++ll) {
            int Hh = 512 >> ll;
            int Ho = Hh - HALO;
            float cnt = 3.f * (float)Ho * (float)Ho;
            float val = (red[ll * 16 + bb][0] + red[ll * 16 + bb][1] +
                         red[ll * 16 + bb][2] + red[ll * 16 + bb][3]) / cnt;
            val = fmaxf(val, 1e-8f);
            ms *= powf(val, wraw[ll] / wsum);
        }
        out[bb] = 1.f - ms;
    }
}

extern "C" void kernel_launch(void* const* d_in, const int* in_sizes, int n_in,
                              void* d_out, int out_size, void* d_ws, size_t ws_size,
                              hipStream_t stream)
{
    const float* X0 = (const float*)d_in[0];
    const float* Y0 = (const float*)d_in[1];
    float* out = (float*)d_out;
    float* ws  = (float*)d_ws;

    // ws layout (floats): P[4][NBIN][16] | X1 | Y1 | X2 | Y2 | X3 | Y3
    const size_t PSZ = (size_t)4 * NBIN * 16;
    float* P  = ws;
    float* X1 = ws + PSZ;
    float* Y1 = X1 + (size_t)16 * 3 * 256 * 256;
    float* X2 = Y1 + (size_t)16 * 3 * 256 * 256;
    float* Y2 = X2 + (size_t)16 * 3 * 128 * 128;
    float* X3 = Y2 + (size_t)16 * 3 * 128 * 128;
    float* Y3 = X3 + (size_t)16 * 3 * 64 * 64;

    GaussW gw;
    {
        float s = 0.f;
        for (int i = 0; i < 11; ++i) {
            float d = (float)(i - 5);
            gw.g[i] = expf(-d * d / (2.f * 1.5f * 1.5f));
            s += gw.g[i];
        }
        for (int i = 0; i < 11; ++i) gw.g[i] /= s;
    }

    hipMemsetAsync(P, 0, PSZ * sizeof(float), stream);

    hipLaunchKernelGGL(ssim_level_kernel, dim3(16, 16, 48), dim3(256), 0, stream,
                       X0, Y0, 512, gw, P + 0 * NBIN * 16, 0, X1, Y1);
    hipLaunchKernelGGL(ssim_level_kernel, dim3(8, 8, 48),   dim3(256), 0, stream,
                       X1, Y1, 256, gw, P + 1 * NBIN * 16, 0, X2, Y2);
    hipLaunchKernelGGL(ssim_level_kernel, dim3(4, 4, 48),   dim3(256), 0, stream,
                       X2, Y2, 128, gw, P + 2 * NBIN * 16, 0, X3, Y3);
    hipLaunchKernelGGL(ssim_level_kernel, dim3(2, 2, 48),   dim3(256), 0, stream,
                       X3, Y3, 64,  gw, P + 3 * NBIN * 16, 1, (float*)nullptr, (float*)nullptr);

    hipLaunchKernelGGL(finalize_kernel, dim3(1), dim3(256), 0, stream, P, out);
}